// Round 7
// baseline (480.043 us; speedup 1.0000x reference)
//
#include <hip/hip_runtime.h>
#include <hip/hip_bf16.h>
#include <stdint.h>

#define IN_DIM 256
#define HID 16
#define OUTD 10
#define BKT_SHIFT 7            // 128 nodes per bucket
#define BKT_W 128
#define PART_CH 2048           // edges per partition block
#define EPT 8                  // edges per thread in part (PART_CH/256)

typedef short v8s __attribute__((ext_vector_type(8)));
typedef float v4f __attribute__((ext_vector_type(4)));

__device__ __forceinline__ float bf2f(unsigned short u) {
    return __uint_as_float(((unsigned int)u) << 16);
}
__device__ __forceinline__ unsigned short f2bf(float f) {
    unsigned int u = __float_as_uint(f);
    unsigned int lsb = (u >> 16) & 1u;
    u += 0x7fffu + lsb;  // round-to-nearest-even
    return (unsigned short)(u >> 16);
}

__device__ __forceinline__ int load_dst(const void* ei, int n_edges, int e, int is64) {
    return is64 ? (int)((const long long*)ei)[(size_t)n_edges + e]
                : ((const int*)ei)[(size_t)n_edges + e];
}
__device__ __forceinline__ int load_src(const void* ei, int n_edges, int e, int is64) {
    return is64 ? (int)((const long long*)ei)[e] : ((const int*)ei)[e];
}

// ---------------- setup: parallel dtype detect + zero bucket counters -------
__global__ void setup_kernel(const void* __restrict__ x,
                             const void* __restrict__ W1,
                             const void* __restrict__ ei,
                             int n_nodes, int* __restrict__ flags,
                             int* __restrict__ bucket_cnt, int K) {
    int t = threadIdx.x;
    for (int i = t; i < K; i += blockDim.x) bucket_cnt[i] = 0;
    if (t < 64) {
        const unsigned short* xs = (const unsigned short*)x;
        const unsigned short* ws = (const unsigned short*)W1;
        bool badx = false, badw = false;
#pragma unroll
        for (int q = 0; q < 4; ++q) {
            float vx = bf2f(xs[t + 64 * q]);
            float vw = bf2f(ws[t + 64 * q]);
            if (!(vx > -1e4f && vx < 1e4f)) badx = true;
            if (!(vw > -1e4f && vw < 1e4f)) badw = true;
        }
        const unsigned long long* e64 = (const unsigned long long*)ei;
        bool big = false;
#pragma unroll
        for (int q = 0; q < 2; ++q)
            if (e64[t + 64 * q] >= (unsigned long long)n_nodes) big = true;
        int xf32 = __any(badx) ? 1 : 0;
        int wf32 = __any(badw) ? 1 : 0;
        int is64 = __any(big) ? 0 : 1;
        if (t == 0) { flags[0] = is64; flags[1] = xf32; flags[2] = wf32; }
    }
}

// ---------------- bucket histogram ------------------------------------------
__global__ void bhist_kernel(const void* __restrict__ ei, int n_edges,
                             int* __restrict__ bucket_cnt,
                             const int* __restrict__ flags, int K) {
    extern __shared__ int lh[];
    for (int i = threadIdx.x; i < K; i += blockDim.x) lh[i] = 0;
    __syncthreads();
    int is64 = flags[0];
    int t = blockIdx.x * blockDim.x + threadIdx.x;
    int stride = gridDim.x * blockDim.x;
    for (int e = t; e < n_edges; e += stride) {
        int d = load_dst(ei, n_edges, e, is64);
        atomicAdd(&lh[d >> BKT_SHIFT], 1);
    }
    __syncthreads();
    for (int i = threadIdx.x; i < K; i += blockDim.x)
        if (lh[i]) atomicAdd(&bucket_cnt[i], lh[i]);
}

// ---------------- bucket scan (1 block) -------------------------------------
__global__ void bscan_kernel(const int* __restrict__ bucket_cnt, int K,
                             int* __restrict__ bucket_off, int* __restrict__ bcur,
                             int* __restrict__ row_off, int n_nodes, int n_edges) {
    __shared__ int ts[256];
    int t = threadIdx.x;
    const int KP = (K + 255) / 256;   // <= 8
    int base = t * KP;
    int local[8];
    int s = 0;
    for (int q = 0; q < KP; ++q) {
        int idx = base + q;
        int v = (idx < K) ? bucket_cnt[idx] : 0;
        local[q] = v; s += v;
    }
    ts[t] = s;
    __syncthreads();
    for (int off = 1; off < 256; off <<= 1) {
        int v = (t >= off) ? ts[t - off] : 0;
        __syncthreads();
        ts[t] += v;
        __syncthreads();
    }
    int ex = ts[t] - s;
    for (int q = 0; q < KP; ++q) {
        int idx = base + q;
        if (idx < K) { bucket_off[idx] = ex; bcur[idx] = ex; }
        ex += local[q];
    }
    if (t == 255) bucket_off[K] = ex;
    if (t == 0) row_off[n_nodes] = n_edges;
}

// ---------------- partition into bucket-major pairs -------------------------
__global__ void part_kernel(const void* __restrict__ ei, int n_edges,
                            int* __restrict__ bcur, uint2* __restrict__ pairs,
                            const int* __restrict__ flags, int K) {
    extern __shared__ int lh[];
    int begin = blockIdx.x * PART_CH;
    int is64 = flags[0];
    for (int i = threadIdx.x; i < K; i += blockDim.x) lh[i] = 0;

    int dloc[EPT];
#pragma unroll
    for (int i = 0; i < EPT; ++i) {
        int e = begin + i * 256 + threadIdx.x;
        dloc[i] = (e < n_edges) ? load_dst(ei, n_edges, e, is64) : -1;
    }
    __syncthreads();
#pragma unroll
    for (int i = 0; i < EPT; ++i)
        if (dloc[i] >= 0) atomicAdd(&lh[dloc[i] >> BKT_SHIFT], 1);
    __syncthreads();
    for (int i = threadIdx.x; i < K; i += blockDim.x) {
        int c = lh[i];
        lh[i] = c ? atomicAdd(&bcur[i], c) : 0;   // reserved run start
    }
    __syncthreads();
#pragma unroll
    for (int i = 0; i < EPT; ++i) {
        int e = begin + i * 256 + threadIdx.x;
        if (dloc[i] >= 0) {
            int s = load_src(ei, n_edges, e, is64);
            int pos = atomicAdd(&lh[dloc[i] >> BKT_SHIFT], 1);
            pairs[pos] = make_uint2((unsigned)s, (unsigned)dloc[i]);
        }
    }
}

// ---------------- per-bucket CSR build --------------------------------------
__global__ void csr_kernel(const uint2* __restrict__ pairs,
                           const int* __restrict__ bucket_off,
                           int* __restrict__ row_off, int* __restrict__ csr_src,
                           int n_nodes) {
    __shared__ int deg[BKT_W];
    __shared__ int cur[BKT_W];
    __shared__ int ts[BKT_W];
    int blk = blockIdx.x;
    int nbase = blk << BKT_SHIFT;
    int NL = n_nodes - nbase; if (NL > BKT_W) NL = BKT_W;
    int beg = bucket_off[blk], end = bucket_off[blk + 1];
    int t = threadIdx.x;
    if (t < BKT_W) deg[t] = 0;
    __syncthreads();
    for (int k = beg + t; k < end; k += blockDim.x)
        atomicAdd(&deg[pairs[k].y & (BKT_W - 1)], 1);
    __syncthreads();
    if (t < BKT_W) ts[t] = deg[t];
    __syncthreads();
    for (int off = 1; off < BKT_W; off <<= 1) {
        int v = 0;
        if (t < BKT_W && t >= off) v = ts[t - off];
        __syncthreads();
        if (t < BKT_W) ts[t] += v;
        __syncthreads();
    }
    if (t < BKT_W) {
        int ex = beg + ts[t] - deg[t];
        cur[t] = ex;
        if (t < NL) row_off[nbase + t] = ex;
    }
    __syncthreads();
    for (int k = beg + t; k < end; k += blockDim.x) {
        uint2 p = pairs[k];
        int pos = atomicAdd(&cur[p.y & (BKT_W - 1)], 1);
        csr_src[pos] = (int)p.x;
    }
}

// ---------------- gemm1 (MFMA): m1 = x @ W1, x must be bf16 -----------------
// W1 (fp32 or bf16) converted to bf16 during LDS staging, frag-major.
__global__ void gemm1_mfma_kernel(const unsigned short* __restrict__ x,
                                  const void* __restrict__ W1p,
                                  float* __restrict__ m1, int n_nodes,
                                  const int* __restrict__ flags) {
    if (flags[1]) return;              // fp32 x -> VALU fallback handles
    const int wf32 = flags[2];
    __shared__ unsigned short Bl[8 * 64 * 8];  // [kk][lane][j], 8 KiB
    int t = threadIdx.x;
    for (int i = t; i < 4096; i += 256) {      // i = k*16 + n
        unsigned short w = wf32 ? f2bf(((const float*)W1p)[i])
                                : ((const unsigned short*)W1p)[i];
        int k = i >> 4, n = i & 15;
        int kk = k >> 5, quad = (k >> 3) & 3, j = k & 7;
        Bl[((kk * 4 + quad) * 16 + n) * 8 + j] = w;
    }
    __syncthreads();

    int lane = t & 63;
    int wave = t >> 6;
    v8s bfrag[8];
#pragma unroll
    for (int kk = 0; kk < 8; ++kk)
        bfrag[kk] = *(const v8s*)&Bl[(kk * 64 + lane) * 8];

    int col  = lane & 15;
    int quad = lane >> 4;
    int n_tiles = (n_nodes + 15) >> 4;
    int gw = blockIdx.x * 4 + wave;
    int nw = gridDim.x * 4;
    for (int tile = gw; tile < n_tiles; tile += nw) {
        int row = tile * 16 + col;               // A-operand m = lane&15
        int r = row < n_nodes ? row : n_nodes - 1;
        const unsigned short* xp = x + (size_t)r * IN_DIM + quad * 8;
        v4f acc = {0.f, 0.f, 0.f, 0.f};
#pragma unroll
        for (int kk = 0; kk < 8; ++kk) {
            v8s a = *(const v8s*)(xp + kk * 32);
            acc = __builtin_amdgcn_mfma_f32_16x16x32_bf16(a, bfrag[kk], acc, 0, 0, 0);
        }
#pragma unroll
        for (int rg = 0; rg < 4; ++rg) {         // C: row=quad*4+rg, col=lane&15
            int node = tile * 16 + quad * 4 + rg;
            if (node < n_nodes) m1[(size_t)node * HID + col] = acc[rg];
        }
    }
}

// ---------------- gemm1 fallback (fp32 x), grid-stride ----------------------
__global__ void gemm1_valu_kernel(const void* __restrict__ xp,
                                  const void* __restrict__ W1p,
                                  float* __restrict__ m1, int n_nodes,
                                  const int* __restrict__ flags) {
    const int xf32 = flags[1], wf32 = flags[2];
    if (!xf32) return;                 // MFMA kernel handled it
    __shared__ float Ws[IN_DIM * HID];
    for (int r = threadIdx.x; r < IN_DIM * HID; r += blockDim.x)
        Ws[r] = wf32 ? ((const float*)W1p)[r]
                     : bf2f(((const unsigned short*)W1p)[r]);
    __syncthreads();
    int total = n_nodes * HID;
    int stride = gridDim.x * blockDim.x;
    for (int tt = blockIdx.x * blockDim.x + threadIdx.x; tt < total; tt += stride) {
        int i = tt >> 4, j = tt & 15;
        float acc = 0.f;
        const float* xr = (const float*)xp + (size_t)i * IN_DIM;
        for (int k = 0; k < IN_DIM; ++k) acc = fmaf(xr[k], Ws[k * HID + j], acc);
        m1[(size_t)i * HID + j] = acc;
    }
}

// ---------------- gather-sum core: 4 lanes/node, unroll-8 for MLP -----------
__device__ __forceinline__ float4 gather_sum16(const float* __restrict__ src,
                                               const int* __restrict__ csr_src,
                                               int beg, int end, int q) {
    float ax = 0.f, ay = 0.f, az = 0.f, aw = 0.f;
    int k = beg;
    for (; k + 8 <= end; k += 8) {
        int s0 = csr_src[k + 0], s1 = csr_src[k + 1];
        int s2 = csr_src[k + 2], s3 = csr_src[k + 3];
        int s4 = csr_src[k + 4], s5 = csr_src[k + 5];
        int s6 = csr_src[k + 6], s7 = csr_src[k + 7];
        float4 v0 = *((const float4*)(src + (size_t)s0 * HID) + q);
        float4 v1 = *((const float4*)(src + (size_t)s1 * HID) + q);
        float4 v2 = *((const float4*)(src + (size_t)s2 * HID) + q);
        float4 v3 = *((const float4*)(src + (size_t)s3 * HID) + q);
        float4 v4 = *((const float4*)(src + (size_t)s4 * HID) + q);
        float4 v5 = *((const float4*)(src + (size_t)s5 * HID) + q);
        float4 v6 = *((const float4*)(src + (size_t)s6 * HID) + q);
        float4 v7 = *((const float4*)(src + (size_t)s7 * HID) + q);
        ax += ((v0.x + v1.x) + (v2.x + v3.x)) + ((v4.x + v5.x) + (v6.x + v7.x));
        ay += ((v0.y + v1.y) + (v2.y + v3.y)) + ((v4.y + v5.y) + (v6.y + v7.y));
        az += ((v0.z + v1.z) + (v2.z + v3.z)) + ((v4.z + v5.z) + (v6.z + v7.z));
        aw += ((v0.w + v1.w) + (v2.w + v3.w)) + ((v4.w + v5.w) + (v6.w + v7.w));
    }
    for (; k < end; ++k) {
        int s = csr_src[k];
        float4 v = *((const float4*)(src + (size_t)s * HID) + q);
        ax += v.x; ay += v.y; az += v.z; aw += v.w;
    }
    return make_float4(ax, ay, az, aw);
}

// ---------------- agg1: h = relu(A . m1 + b1) -------------------------------
__global__ void agg1_kernel(const float* __restrict__ m1,
                            const int* __restrict__ row_off,
                            const int* __restrict__ csr_src,
                            const void* __restrict__ b1p,
                            float* __restrict__ h, int n_nodes,
                            const int* __restrict__ flags) {
    int t = blockIdx.x * blockDim.x + threadIdx.x;
    int node = t >> 2;
    if (node >= n_nodes) return;
    int q = t & 3;
    const int wf32 = flags[2];
    float4 a = gather_sum16(m1, csr_src, row_off[node], row_off[node + 1], q);
    float b0, b1v, b2v, b3;
    if (wf32) {
        const float* b = (const float*)b1p + q * 4;
        b0 = b[0]; b1v = b[1]; b2v = b[2]; b3 = b[3];
    } else {
        const unsigned short* b = (const unsigned short*)b1p + q * 4;
        b0 = bf2f(b[0]); b1v = bf2f(b[1]); b2v = bf2f(b[2]); b3 = bf2f(b[3]);
    }
    float4 r;
    r.x = fmaxf(a.x + b0, 0.f);
    r.y = fmaxf(a.y + b1v, 0.f);
    r.z = fmaxf(a.z + b2v, 0.f);
    r.w = fmaxf(a.w + b3, 0.f);
    *((float4*)(h + (size_t)node * HID) + q) = r;
}

// ---------------- agg2: aggh = A . h ----------------------------------------
__global__ void agg2_kernel(const float* __restrict__ h,
                            const int* __restrict__ row_off,
                            const int* __restrict__ csr_src,
                            float* __restrict__ aggh, int n_nodes) {
    int t = blockIdx.x * blockDim.x + threadIdx.x;
    int node = t >> 2;
    if (node >= n_nodes) return;
    int q = t & 3;
    float4 a = gather_sum16(h, csr_src, row_off[node], row_off[node + 1], q);
    *((float4*)(aggh + (size_t)node * HID) + q) = a;
}

// ---------------- out: out = aggh @ W2 + b2 (assoc: A(hW2) = (Ah)W2) --------
__global__ void out_kernel(const float* __restrict__ aggh,
                           const void* __restrict__ W2p,
                           const void* __restrict__ b2p,
                           void* __restrict__ out, int n_nodes,
                           const int* __restrict__ flags) {
    __shared__ float Ws[HID * OUTD];
    __shared__ float bs[OUTD];
    const int xf32 = flags[1], wf32 = flags[2];
    if (threadIdx.x < HID * OUTD)
        Ws[threadIdx.x] = wf32 ? ((const float*)W2p)[threadIdx.x]
                               : bf2f(((const unsigned short*)W2p)[threadIdx.x]);
    if (threadIdx.x < OUTD)
        bs[threadIdx.x] = wf32 ? ((const float*)b2p)[threadIdx.x]
                               : bf2f(((const unsigned short*)b2p)[threadIdx.x]);
    __syncthreads();

    int i = blockIdx.x * blockDim.x + threadIdx.x;
    if (i >= n_nodes) return;

    float hv[HID];
    const float4* a = (const float4*)(aggh + (size_t)i * HID);
#pragma unroll
    for (int q = 0; q < 4; ++q) {
        float4 v = a[q];
        hv[q * 4 + 0] = v.x; hv[q * 4 + 1] = v.y;
        hv[q * 4 + 2] = v.z; hv[q * 4 + 3] = v.w;
    }
    float o[OUTD];
#pragma unroll
    for (int od = 0; od < OUTD; ++od) {
        float s = bs[od];
#pragma unroll
        for (int c = 0; c < HID; ++c) s = fmaf(hv[c], Ws[c * OUTD + od], s);
        o[od] = s;
    }
    if (xf32) {
        float* po = (float*)out + (size_t)i * OUTD;
#pragma unroll
        for (int od = 0; od < OUTD; ++od) po[od] = o[od];
    } else {
        unsigned int* po = (unsigned int*)((unsigned short*)out + (size_t)i * OUTD);
#pragma unroll
        for (int q = 0; q < 5; ++q)
            po[q] = (unsigned int)f2bf(o[2 * q]) | ((unsigned int)f2bf(o[2 * q + 1]) << 16);
    }
}

// ---------------- Sentinel: ws_size too small -------------------------------
__global__ void sentinel_kernel(float* __restrict__ out) {
    if (blockIdx.x == 0 && threadIdx.x < 16) out[threadIdx.x] = 123456.0f;
}

extern "C" void kernel_launch(void* const* d_in, const int* in_sizes, int n_in,
                              void* d_out, int out_size, void* d_ws, size_t ws_size,
                              hipStream_t stream) {
    const void* x  = d_in[0];
    const void* ei = d_in[1];
    const void* W1 = d_in[2];
    const void* b1 = d_in[3];
    const void* W2 = d_in[4];
    const void* b2 = d_in[5];

    const int n_nodes = in_sizes[0] / IN_DIM;        // 100000
    const int n_edges = in_sizes[1] / 2;             // 3200000
    const int K = (n_nodes + BKT_W - 1) / BKT_W;     // 782 buckets

    // Workspace layout (256B-aligned):
    // [flags | bucket_cnt | bucket_off | bcur | row_off | csr_src |
    //  pairs-region (aliases m1,h,aggh after csr build)]
    char* p = (char*)d_ws;
    auto align = [](size_t v) { return (v + 255) & ~(size_t)255; };
    size_t off = 0;
    int* flags      = (int*)(p + off); off = align(off + 256);
    int* bucket_cnt = (int*)(p + off); off = align(off + (size_t)K * 4);
    int* bucket_off = (int*)(p + off); off = align(off + ((size_t)K + 1) * 4);
    int* bcur       = (int*)(p + off); off = align(off + (size_t)K * 4);
    int* row_off    = (int*)(p + off); off = align(off + ((size_t)n_nodes + 1) * 4);
    int* csr_src    = (int*)(p + off); off = align(off + (size_t)n_edges * 4);
    size_t alias_base = off;
    uint2* pairs = (uint2*)(p + alias_base);
    float* m1    = (float*)(p + alias_base);          // aliases pairs (stream-ordered)
    float* h     = m1 + (size_t)n_nodes * HID;
    float* aggh  = h  + (size_t)n_nodes * HID;
    size_t alias_sz = (size_t)n_edges * 8;            // pairs is the larger user
    size_t mhm_sz = (size_t)n_nodes * (HID * 3) * 4;
    if (mhm_sz > alias_sz) alias_sz = mhm_sz;
    off = align(alias_base + alias_sz);

    if (ws_size < off) {
        sentinel_kernel<<<1, 64, 0, stream>>>((float*)d_out);
        return;
    }

    const size_t lds_k = (size_t)K * 4;

    // --- CSR build (bucketed, line-efficient writes) ---
    setup_kernel<<<1, 256, 0, stream>>>(x, W1, ei, n_nodes, flags, bucket_cnt, K);
    bhist_kernel<<<1024, 256, lds_k, stream>>>(ei, n_edges, bucket_cnt, flags, K);
    bscan_kernel<<<1, 256, 0, stream>>>(bucket_cnt, K, bucket_off, bcur,
                                        row_off, n_nodes, n_edges);
    part_kernel<<<(n_edges + PART_CH - 1) / PART_CH, 256, lds_k, stream>>>(
        ei, n_edges, bcur, pairs, flags, K);
    csr_kernel<<<K, 256, 0, stream>>>(pairs, bucket_off, row_off, csr_src, n_nodes);

    // --- layer 1 ---
    gemm1_mfma_kernel<<<512, 256, 0, stream>>>(
        (const unsigned short*)x, W1, m1, n_nodes, flags);
    gemm1_valu_kernel<<<512, 256, 0, stream>>>(x, W1, m1, n_nodes, flags);
    {
        long long threads = (long long)n_nodes * 4;
        agg1_kernel<<<(int)((threads + 255) / 256), 256, 0, stream>>>(
            m1, row_off, csr_src, b1, h, n_nodes, flags);
    }

    // --- layer 2 (assoc: out = (A.h)@W2 + b2) ---
    {
        long long threads = (long long)n_nodes * 4;
        agg2_kernel<<<(int)((threads + 255) / 256), 256, 0, stream>>>(
            h, row_off, csr_src, aggh, n_nodes);
    }
    out_kernel<<<(n_nodes + 255) / 256, 256, 0, stream>>>(
        aggh, W2, b2, d_out, n_nodes, flags);
}

// Round 8
// 385.040 us; speedup vs baseline: 1.2467x; 1.2467x over previous
//
#include <hip/hip_runtime.h>
#include <hip/hip_bf16.h>
#include <stdint.h>

#define IN_DIM 256
#define HID 16
#define OUTD 10
#define BKT_SHIFT 7            // 128 nodes per bucket
#define BKT_W 128
#define PART_CH 8192           // edges per partition block
#define EPT 32                 // edges per thread in part (PART_CH/256)

typedef short v8s __attribute__((ext_vector_type(8)));
typedef float v4f __attribute__((ext_vector_type(4)));

__device__ __forceinline__ float bf2f(unsigned short u) {
    return __uint_as_float(((unsigned int)u) << 16);
}
__device__ __forceinline__ unsigned short f2bf(float f) {
    unsigned int u = __float_as_uint(f);
    unsigned int lsb = (u >> 16) & 1u;
    u += 0x7fffu + lsb;  // round-to-nearest-even
    return (unsigned short)(u >> 16);
}

__device__ __forceinline__ int load_dst(const void* ei, int n_edges, int e, int is64) {
    return is64 ? (int)((const long long*)ei)[(size_t)n_edges + e]
                : ((const int*)ei)[(size_t)n_edges + e];
}
__device__ __forceinline__ int load_src(const void* ei, int n_edges, int e, int is64) {
    return is64 ? (int)((const long long*)ei)[e] : ((const int*)ei)[e];
}

// ---------------- setup: parallel dtype detect + zero bucket counters -------
__global__ void setup_kernel(const void* __restrict__ x,
                             const void* __restrict__ W1,
                             const void* __restrict__ ei,
                             int n_nodes, int* __restrict__ flags,
                             int* __restrict__ bucket_cnt, int K) {
    int t = threadIdx.x;
    for (int i = t; i < K; i += blockDim.x) bucket_cnt[i] = 0;
    if (t < 64) {
        const unsigned short* xs = (const unsigned short*)x;
        const unsigned short* ws = (const unsigned short*)W1;
        bool badx = false, badw = false;
#pragma unroll
        for (int q = 0; q < 4; ++q) {
            float vx = bf2f(xs[t + 64 * q]);
            float vw = bf2f(ws[t + 64 * q]);
            if (!(vx > -1e4f && vx < 1e4f)) badx = true;
            if (!(vw > -1e4f && vw < 1e4f)) badw = true;
        }
        const unsigned long long* e64 = (const unsigned long long*)ei;
        bool big = false;
#pragma unroll
        for (int q = 0; q < 2; ++q)
            if (e64[t + 64 * q] >= (unsigned long long)n_nodes) big = true;
        int xf32 = __any(badx) ? 1 : 0;
        int wf32 = __any(badw) ? 1 : 0;
        int is64 = __any(big) ? 0 : 1;
        if (t == 0) { flags[0] = is64; flags[1] = xf32; flags[2] = wf32; }
    }
}

// ---------------- bucket histogram ------------------------------------------
__global__ void bhist_kernel(const void* __restrict__ ei, int n_edges,
                             int* __restrict__ bucket_cnt,
                             const int* __restrict__ flags, int K) {
    extern __shared__ int lh[];
    for (int i = threadIdx.x; i < K; i += blockDim.x) lh[i] = 0;
    __syncthreads();
    int is64 = flags[0];
    int t = blockIdx.x * blockDim.x + threadIdx.x;
    int stride = gridDim.x * blockDim.x;
    for (int e = t; e < n_edges; e += stride) {
        int d = load_dst(ei, n_edges, e, is64);
        atomicAdd(&lh[d >> BKT_SHIFT], 1);
    }
    __syncthreads();
    for (int i = threadIdx.x; i < K; i += blockDim.x)
        if (lh[i]) atomicAdd(&bucket_cnt[i], lh[i]);
}

// ---------------- bucket scan (1 block) -------------------------------------
__global__ void bscan_kernel(const int* __restrict__ bucket_cnt, int K,
                             int* __restrict__ bucket_off, int* __restrict__ bcur,
                             int* __restrict__ row_off, int n_nodes, int n_edges) {
    __shared__ int ts[256];
    int t = threadIdx.x;
    const int KP = (K + 255) / 256;   // <= 8
    int base = t * KP;
    int local[8];
    int s = 0;
    for (int q = 0; q < KP; ++q) {
        int idx = base + q;
        int v = (idx < K) ? bucket_cnt[idx] : 0;
        local[q] = v; s += v;
    }
    ts[t] = s;
    __syncthreads();
    for (int off = 1; off < 256; off <<= 1) {
        int v = (t >= off) ? ts[t - off] : 0;
        __syncthreads();
        ts[t] += v;
        __syncthreads();
    }
    int ex = ts[t] - s;
    for (int q = 0; q < KP; ++q) {
        int idx = base + q;
        if (idx < K) { bucket_off[idx] = ex; bcur[idx] = ex; }
        ex += local[q];
    }
    if (t == 255) bucket_off[K] = ex;
    if (t == 0) row_off[n_nodes] = n_edges;
}

// ---------------- partition into bucket-major packed pairs ------------------
// pair = (src << 7) | (dst & 127): 4B instead of 8B.
__global__ void part_kernel(const void* __restrict__ ei, int n_edges,
                            int* __restrict__ bcur, unsigned int* __restrict__ pairs,
                            const int* __restrict__ flags, int K) {
    extern __shared__ int lh[];
    int begin = blockIdx.x * PART_CH;
    int is64 = flags[0];
    for (int i = threadIdx.x; i < K; i += blockDim.x) lh[i] = 0;

    int dloc[EPT];
#pragma unroll
    for (int i = 0; i < EPT; ++i) {
        int e = begin + i * 256 + threadIdx.x;
        dloc[i] = (e < n_edges) ? load_dst(ei, n_edges, e, is64) : -1;
    }
    __syncthreads();
#pragma unroll
    for (int i = 0; i < EPT; ++i)
        if (dloc[i] >= 0) atomicAdd(&lh[dloc[i] >> BKT_SHIFT], 1);
    __syncthreads();
    for (int i = threadIdx.x; i < K; i += blockDim.x) {
        int c = lh[i];
        lh[i] = c ? atomicAdd(&bcur[i], c) : 0;   // reserved run start
    }
    __syncthreads();
#pragma unroll
    for (int i = 0; i < EPT; ++i) {
        int e = begin + i * 256 + threadIdx.x;
        if (dloc[i] >= 0) {
            int s = load_src(ei, n_edges, e, is64);
            int pos = atomicAdd(&lh[dloc[i] >> BKT_SHIFT], 1);
            pairs[pos] = ((unsigned)s << 7) | ((unsigned)dloc[i] & (BKT_W - 1));
        }
    }
}

// ---------------- per-bucket CSR build --------------------------------------
__global__ void csr_kernel(const unsigned int* __restrict__ pairs,
                           const int* __restrict__ bucket_off,
                           int* __restrict__ row_off, int* __restrict__ csr_src,
                           int n_nodes) {
    __shared__ int deg[BKT_W];
    __shared__ int cur[BKT_W];
    __shared__ int ts[BKT_W];
    int blk = blockIdx.x;
    int nbase = blk << BKT_SHIFT;
    int NL = n_nodes - nbase; if (NL > BKT_W) NL = BKT_W;
    int beg = bucket_off[blk], end = bucket_off[blk + 1];
    int t = threadIdx.x;
    if (t < BKT_W) deg[t] = 0;
    __syncthreads();
    for (int k = beg + t; k < end; k += blockDim.x)
        atomicAdd(&deg[pairs[k] & (BKT_W - 1)], 1);
    __syncthreads();
    if (t < BKT_W) ts[t] = deg[t];
    __syncthreads();
    for (int off = 1; off < BKT_W; off <<= 1) {
        int v = 0;
        if (t < BKT_W && t >= off) v = ts[t - off];
        __syncthreads();
        if (t < BKT_W) ts[t] += v;
        __syncthreads();
    }
    if (t < BKT_W) {
        int ex = beg + ts[t] - deg[t];
        cur[t] = ex;
        if (t < NL) row_off[nbase + t] = ex;
    }
    __syncthreads();
    for (int k = beg + t; k < end; k += blockDim.x) {
        unsigned int p = pairs[k];
        int pos = atomicAdd(&cur[p & (BKT_W - 1)], 1);
        csr_src[pos] = (int)(p >> 7);
    }
}

// ---------------- gemm1 (MFMA, bf16 x): m1 = x @ W1 -------------------------
__global__ void gemm1_mfma_bf16x(const unsigned short* __restrict__ x,
                                 const void* __restrict__ W1p,
                                 float* __restrict__ m1, int n_nodes,
                                 const int* __restrict__ flags) {
    if (flags[1]) return;              // fp32 x handled elsewhere
    const int wf32 = flags[2];
    __shared__ unsigned short Bl[8 * 64 * 8];  // [kk][lane][j], 8 KiB
    int t = threadIdx.x;
    for (int i = t; i < 4096; i += 256) {      // i = k*16 + n
        unsigned short w = wf32 ? f2bf(((const float*)W1p)[i])
                                : ((const unsigned short*)W1p)[i];
        int k = i >> 4, n = i & 15;
        int kk = k >> 5, quad = (k >> 3) & 3, j = k & 7;
        Bl[((kk * 4 + quad) * 16 + n) * 8 + j] = w;
    }
    __syncthreads();

    int lane = t & 63;
    int wave = t >> 6;
    v8s bfrag[8];
#pragma unroll
    for (int kk = 0; kk < 8; ++kk)
        bfrag[kk] = *(const v8s*)&Bl[(kk * 64 + lane) * 8];

    int col  = lane & 15;
    int quad = lane >> 4;
    int n_tiles = (n_nodes + 15) >> 4;
    for (int tile = blockIdx.x * 4 + wave; tile < n_tiles; tile += gridDim.x * 4) {
        int row = tile * 16 + col;
        int r = row < n_nodes ? row : n_nodes - 1;
        const unsigned short* xp = x + (size_t)r * IN_DIM + quad * 8;
        v4f acc = {0.f, 0.f, 0.f, 0.f};
#pragma unroll
        for (int kk = 0; kk < 8; ++kk) {
            v8s a = *(const v8s*)(xp + kk * 32);
            acc = __builtin_amdgcn_mfma_f32_16x16x32_bf16(a, bfrag[kk], acc, 0, 0, 0);
        }
#pragma unroll
        for (int rg = 0; rg < 4; ++rg) {
            int node = tile * 16 + quad * 4 + rg;
            if (node < n_nodes) m1[(size_t)node * HID + col] = acc[rg];
        }
    }
}

// ---------------- gemm1 (MFMA, fp32 x): split-bf16, fp32-grade precision ----
// x = hi + lo (bf16 each); acc += hi*Bhi + hi*Blo + lo*Bhi  (err ~2^-18 rel)
__global__ void gemm1_mfma_f32x(const float* __restrict__ x,
                                const void* __restrict__ W1p,
                                float* __restrict__ m1, int n_nodes,
                                const int* __restrict__ flags) {
    if (!flags[1]) return;             // bf16 x handled elsewhere
    const int wf32 = flags[2];
    __shared__ unsigned short Bhi[8 * 64 * 8];
    __shared__ unsigned short Blo[8 * 64 * 8];
    int t = threadIdx.x;
    for (int i = t; i < 4096; i += 256) {
        float w = wf32 ? ((const float*)W1p)[i]
                       : bf2f(((const unsigned short*)W1p)[i]);
        unsigned short hi = f2bf(w);
        unsigned short lo = f2bf(w - bf2f(hi));
        int k = i >> 4, n = i & 15;
        int kk = k >> 5, quad = (k >> 3) & 3, j = k & 7;
        int idx = ((kk * 4 + quad) * 16 + n) * 8 + j;
        Bhi[idx] = hi; Blo[idx] = lo;
    }
    __syncthreads();

    int lane = t & 63;
    int wave = t >> 6;
    v8s bhi[8], blo[8];
#pragma unroll
    for (int kk = 0; kk < 8; ++kk) {
        bhi[kk] = *(const v8s*)&Bhi[(kk * 64 + lane) * 8];
        blo[kk] = *(const v8s*)&Blo[(kk * 64 + lane) * 8];
    }

    int col  = lane & 15;
    int quad = lane >> 4;
    int n_tiles = (n_nodes + 15) >> 4;
    for (int tile = blockIdx.x * 4 + wave; tile < n_tiles; tile += gridDim.x * 4) {
        int row = tile * 16 + col;
        int r = row < n_nodes ? row : n_nodes - 1;
        const float* xp = x + (size_t)r * IN_DIM + quad * 8;
        v4f acc = {0.f, 0.f, 0.f, 0.f};
#pragma unroll
        for (int kk = 0; kk < 8; ++kk) {
            float4 u0 = *(const float4*)(xp + kk * 32);
            float4 u1 = *(const float4*)(xp + kk * 32 + 4);
            float uv[8] = {u0.x, u0.y, u0.z, u0.w, u1.x, u1.y, u1.z, u1.w};
            v8s ahi, alo;
#pragma unroll
            for (int j = 0; j < 8; ++j) {
                unsigned short hi = f2bf(uv[j]);
                unsigned short lo = f2bf(uv[j] - bf2f(hi));
                ahi[j] = (short)hi; alo[j] = (short)lo;
            }
            acc = __builtin_amdgcn_mfma_f32_16x16x32_bf16(ahi, bhi[kk], acc, 0, 0, 0);
            acc = __builtin_amdgcn_mfma_f32_16x16x32_bf16(ahi, blo[kk], acc, 0, 0, 0);
            acc = __builtin_amdgcn_mfma_f32_16x16x32_bf16(alo, bhi[kk], acc, 0, 0, 0);
        }
#pragma unroll
        for (int rg = 0; rg < 4; ++rg) {
            int node = tile * 16 + quad * 4 + rg;
            if (node < n_nodes) m1[(size_t)node * HID + col] = acc[rg];
        }
    }
}

// ---------------- gather-sum core: 4 lanes/node, 16-deep MLP ----------------
__device__ __forceinline__ float4 gather_sum16(const float* __restrict__ src,
                                               const int* __restrict__ csr_src,
                                               int beg, int end, int q) {
    float ax = 0.f, ay = 0.f, az = 0.f, aw = 0.f;
    int k = beg;
    for (; k + 16 <= end; k += 16) {
        float4 v[16];
#pragma unroll
        for (int u = 0; u < 16; ++u) {
            int s = csr_src[k + u];
            v[u] = *((const float4*)(src + (size_t)s * HID) + q);
        }
#pragma unroll
        for (int u = 0; u < 16; ++u) {
            ax += v[u].x; ay += v[u].y; az += v[u].z; aw += v[u].w;
        }
    }
    for (; k + 4 <= end; k += 4) {
        float4 v[4];
#pragma unroll
        for (int u = 0; u < 4; ++u) {
            int s = csr_src[k + u];
            v[u] = *((const float4*)(src + (size_t)s * HID) + q);
        }
#pragma unroll
        for (int u = 0; u < 4; ++u) {
            ax += v[u].x; ay += v[u].y; az += v[u].z; aw += v[u].w;
        }
    }
    for (; k < end; ++k) {
        int s = csr_src[k];
        float4 v = *((const float4*)(src + (size_t)s * HID) + q);
        ax += v.x; ay += v.y; az += v.z; aw += v.w;
    }
    return make_float4(ax, ay, az, aw);
}

// ---------------- agg1: h = relu(A . m1 + b1) -------------------------------
__global__ void agg1_kernel(const float* __restrict__ m1,
                            const int* __restrict__ row_off,
                            const int* __restrict__ csr_src,
                            const void* __restrict__ b1p,
                            float* __restrict__ h, int n_nodes,
                            const int* __restrict__ flags) {
    int t = blockIdx.x * blockDim.x + threadIdx.x;
    int node = t >> 2;
    if (node >= n_nodes) return;
    int q = t & 3;
    const int wf32 = flags[2];
    float4 a = gather_sum16(m1, csr_src, row_off[node], row_off[node + 1], q);
    float b0, b1v, b2v, b3;
    if (wf32) {
        const float* b = (const float*)b1p + q * 4;
        b0 = b[0]; b1v = b[1]; b2v = b[2]; b3 = b[3];
    } else {
        const unsigned short* b = (const unsigned short*)b1p + q * 4;
        b0 = bf2f(b[0]); b1v = bf2f(b[1]); b2v = bf2f(b[2]); b3 = bf2f(b[3]);
    }
    float4 r;
    r.x = fmaxf(a.x + b0, 0.f);
    r.y = fmaxf(a.y + b1v, 0.f);
    r.z = fmaxf(a.z + b2v, 0.f);
    r.w = fmaxf(a.w + b3, 0.f);
    *((float4*)(h + (size_t)node * HID) + q) = r;
}

// ---------------- agg2: aggh = A . h ----------------------------------------
__global__ void agg2_kernel(const float* __restrict__ h,
                            const int* __restrict__ row_off,
                            const int* __restrict__ csr_src,
                            float* __restrict__ aggh, int n_nodes) {
    int t = blockIdx.x * blockDim.x + threadIdx.x;
    int node = t >> 2;
    if (node >= n_nodes) return;
    int q = t & 3;
    float4 a = gather_sum16(h, csr_src, row_off[node], row_off[node + 1], q);
    *((float4*)(aggh + (size_t)node * HID) + q) = a;
}

// ---------------- out: out = aggh @ W2 + b2 (assoc: A(hW2) = (Ah)W2) --------
__global__ void out_kernel(const float* __restrict__ aggh,
                           const void* __restrict__ W2p,
                           const void* __restrict__ b2p,
                           void* __restrict__ out, int n_nodes,
                           const int* __restrict__ flags) {
    __shared__ float Ws[HID * OUTD];
    __shared__ float bs[OUTD];
    const int xf32 = flags[1], wf32 = flags[2];
    if (threadIdx.x < HID * OUTD)
        Ws[threadIdx.x] = wf32 ? ((const float*)W2p)[threadIdx.x]
                               : bf2f(((const unsigned short*)W2p)[threadIdx.x]);
    if (threadIdx.x < OUTD)
        bs[threadIdx.x] = wf32 ? ((const float*)b2p)[threadIdx.x]
                               : bf2f(((const unsigned short*)b2p)[threadIdx.x]);
    __syncthreads();

    int i = blockIdx.x * blockDim.x + threadIdx.x;
    if (i >= n_nodes) return;

    float hv[HID];
    const float4* a = (const float4*)(aggh + (size_t)i * HID);
#pragma unroll
    for (int q = 0; q < 4; ++q) {
        float4 v = a[q];
        hv[q * 4 + 0] = v.x; hv[q * 4 + 1] = v.y;
        hv[q * 4 + 2] = v.z; hv[q * 4 + 3] = v.w;
    }
    float o[OUTD];
#pragma unroll
    for (int od = 0; od < OUTD; ++od) {
        float s = bs[od];
#pragma unroll
        for (int c = 0; c < HID; ++c) s = fmaf(hv[c], Ws[c * OUTD + od], s);
        o[od] = s;
    }
    if (xf32) {
        float* po = (float*)out + (size_t)i * OUTD;
#pragma unroll
        for (int od = 0; od < OUTD; ++od) po[od] = o[od];
    } else {
        unsigned int* po = (unsigned int*)((unsigned short*)out + (size_t)i * OUTD);
#pragma unroll
        for (int q = 0; q < 5; ++q)
            po[q] = (unsigned int)f2bf(o[2 * q]) | ((unsigned int)f2bf(o[2 * q + 1]) << 16);
    }
}

// ---------------- Sentinel: ws_size too small -------------------------------
__global__ void sentinel_kernel(float* __restrict__ out) {
    if (blockIdx.x == 0 && threadIdx.x < 16) out[threadIdx.x] = 123456.0f;
}

extern "C" void kernel_launch(void* const* d_in, const int* in_sizes, int n_in,
                              void* d_out, int out_size, void* d_ws, size_t ws_size,
                              hipStream_t stream) {
    const void* x  = d_in[0];
    const void* ei = d_in[1];
    const void* W1 = d_in[2];
    const void* b1 = d_in[3];
    const void* W2 = d_in[4];
    const void* b2 = d_in[5];

    const int n_nodes = in_sizes[0] / IN_DIM;        // 100000
    const int n_edges = in_sizes[1] / 2;             // 3200000
    const int K = (n_nodes + BKT_W - 1) / BKT_W;     // 782 buckets

    // Workspace layout (256B-aligned):
    // [flags | bucket_cnt | bucket_off | bcur | row_off | csr_src |
    //  pairs-region (aliases m1,h,aggh after csr build)]
    char* p = (char*)d_ws;
    auto align = [](size_t v) { return (v + 255) & ~(size_t)255; };
    size_t off = 0;
    int* flags      = (int*)(p + off); off = align(off + 256);
    int* bucket_cnt = (int*)(p + off); off = align(off + (size_t)K * 4);
    int* bucket_off = (int*)(p + off); off = align(off + ((size_t)K + 1) * 4);
    int* bcur       = (int*)(p + off); off = align(off + (size_t)K * 4);
    int* row_off    = (int*)(p + off); off = align(off + ((size_t)n_nodes + 1) * 4);
    int* csr_src    = (int*)(p + off); off = align(off + (size_t)n_edges * 4);
    size_t alias_base = off;
    unsigned int* pairs = (unsigned int*)(p + alias_base);
    float* m1    = (float*)(p + alias_base);          // aliases pairs (stream-ordered)
    float* h     = m1 + (size_t)n_nodes * HID;
    float* aggh  = h  + (size_t)n_nodes * HID;
    size_t alias_sz = (size_t)n_edges * 4;            // packed pairs
    size_t mhm_sz = (size_t)n_nodes * (HID * 3) * 4;
    if (mhm_sz > alias_sz) alias_sz = mhm_sz;
    off = align(alias_base + alias_sz);

    if (ws_size < off) {
        sentinel_kernel<<<1, 64, 0, stream>>>((float*)d_out);
        return;
    }

    const size_t lds_k = (size_t)K * 4;

    // --- CSR build (bucketed, line-efficient writes) ---
    setup_kernel<<<1, 256, 0, stream>>>(x, W1, ei, n_nodes, flags, bucket_cnt, K);
    bhist_kernel<<<1024, 256, lds_k, stream>>>(ei, n_edges, bucket_cnt, flags, K);
    bscan_kernel<<<1, 256, 0, stream>>>(bucket_cnt, K, bucket_off, bcur,
                                        row_off, n_nodes, n_edges);
    part_kernel<<<(n_edges + PART_CH - 1) / PART_CH, 256, lds_k, stream>>>(
        ei, n_edges, bcur, pairs, flags, K);
    csr_kernel<<<K, 256, 0, stream>>>(pairs, bucket_off, row_off, csr_src, n_nodes);

    // --- layer 1 ---
    gemm1_mfma_bf16x<<<512, 256, 0, stream>>>(
        (const unsigned short*)x, W1, m1, n_nodes, flags);
    gemm1_mfma_f32x<<<512, 256, 0, stream>>>(
        (const float*)x, W1, m1, n_nodes, flags);
    {
        long long threads = (long long)n_nodes * 4;
        agg1_kernel<<<(int)((threads + 255) / 256), 256, 0, stream>>>(
            m1, row_off, csr_src, b1, h, n_nodes, flags);
    }

    // --- layer 2 (assoc: out = (A.h)@W2 + b2) ---
    {
        long long threads = (long long)n_nodes * 4;
        agg2_kernel<<<(int)((threads + 255) / 256), 256, 0, stream>>>(
            h, row_off, csr_src, aggh, n_nodes);
    }
    out_kernel<<<(n_nodes + 255) / 256, 256, 0, stream>>>(
        aggh, W2, b2, d_out, n_nodes, flags);
}

// Round 9
// 368.422 us; speedup vs baseline: 1.3030x; 1.0451x over previous
//
#include <hip/hip_runtime.h>
#include <hip/hip_bf16.h>
#include <stdint.h>

#define IN_DIM 256
#define HID 16
#define OUTD 10
#define BKT_SHIFT 8            // 256 nodes per bucket
#define BKT_W 256
#define PART_CH 4096           // edges per partition block
#define EPT 16                 // edges per thread in part (PART_CH/256)

typedef short v8s __attribute__((ext_vector_type(8)));
typedef float v4f __attribute__((ext_vector_type(4)));

__device__ __forceinline__ float bf2f(unsigned short u) {
    return __uint_as_float(((unsigned int)u) << 16);
}
__device__ __forceinline__ unsigned short f2bf(float f) {
    unsigned int u = __float_as_uint(f);
    unsigned int lsb = (u >> 16) & 1u;
    u += 0x7fffu + lsb;  // round-to-nearest-even
    return (unsigned short)(u >> 16);
}

__device__ __forceinline__ int load_dst(const void* ei, int n_edges, int e, int is64) {
    return is64 ? (int)((const long long*)ei)[(size_t)n_edges + e]
                : ((const int*)ei)[(size_t)n_edges + e];
}
__device__ __forceinline__ int load_src(const void* ei, int n_edges, int e, int is64) {
    return is64 ? (int)((const long long*)ei)[e] : ((const int*)ei)[e];
}

// ---------------- setup: parallel dtype detect + zero bucket counters -------
__global__ void setup_kernel(const void* __restrict__ x,
                             const void* __restrict__ W1,
                             const void* __restrict__ ei,
                             int n_nodes, int* __restrict__ flags,
                             int* __restrict__ bucket_cnt, int K) {
    int t = threadIdx.x;
    for (int i = t; i < K; i += blockDim.x) bucket_cnt[i] = 0;
    if (t < 64) {
        const unsigned short* xs = (const unsigned short*)x;
        const unsigned short* ws = (const unsigned short*)W1;
        bool badx = false, badw = false;
#pragma unroll
        for (int q = 0; q < 4; ++q) {
            float vx = bf2f(xs[t + 64 * q]);
            float vw = bf2f(ws[t + 64 * q]);
            if (!(vx > -1e4f && vx < 1e4f)) badx = true;
            if (!(vw > -1e4f && vw < 1e4f)) badw = true;
        }
        const unsigned long long* e64 = (const unsigned long long*)ei;
        bool big = false;
#pragma unroll
        for (int q = 0; q < 2; ++q)
            if (e64[t + 64 * q] >= (unsigned long long)n_nodes) big = true;
        int xf32 = __any(badx) ? 1 : 0;
        int wf32 = __any(badw) ? 1 : 0;
        int is64 = __any(big) ? 0 : 1;
        if (t == 0) { flags[0] = is64; flags[1] = xf32; flags[2] = wf32; }
    }
}

// ---------------- bucket histogram ------------------------------------------
__global__ void bhist_kernel(const void* __restrict__ ei, int n_edges,
                             int* __restrict__ bucket_cnt,
                             const int* __restrict__ flags, int K) {
    extern __shared__ int lh[];
    for (int i = threadIdx.x; i < K; i += blockDim.x) lh[i] = 0;
    __syncthreads();
    int is64 = flags[0];
    int t = blockIdx.x * blockDim.x + threadIdx.x;
    int stride = gridDim.x * blockDim.x;
    for (int e = t; e < n_edges; e += stride) {
        int d = load_dst(ei, n_edges, e, is64);
        atomicAdd(&lh[d >> BKT_SHIFT], 1);
    }
    __syncthreads();
    for (int i = threadIdx.x; i < K; i += blockDim.x)
        if (lh[i]) atomicAdd(&bucket_cnt[i], lh[i]);
}

// ---------------- bucket scan (1 block) -------------------------------------
__global__ void bscan_kernel(const int* __restrict__ bucket_cnt, int K,
                             int* __restrict__ bucket_off, int* __restrict__ bcur,
                             int* __restrict__ row_off, int n_nodes, int n_edges) {
    __shared__ int ts[256];
    int t = threadIdx.x;
    const int KP = (K + 255) / 256;   // <= 8
    int base = t * KP;
    int local[8];
    int s = 0;
    for (int q = 0; q < KP; ++q) {
        int idx = base + q;
        int v = (idx < K) ? bucket_cnt[idx] : 0;
        local[q] = v; s += v;
    }
    ts[t] = s;
    __syncthreads();
    for (int off = 1; off < 256; off <<= 1) {
        int v = (t >= off) ? ts[t - off] : 0;
        __syncthreads();
        ts[t] += v;
        __syncthreads();
    }
    int ex = ts[t] - s;
    for (int q = 0; q < KP; ++q) {
        int idx = base + q;
        if (idx < K) { bucket_off[idx] = ex; bcur[idx] = ex; }
        ex += local[q];
    }
    if (t == 255) bucket_off[K] = ex;
    if (t == 0) row_off[n_nodes] = n_edges;
}

// ---------------- partition: in-LDS counting sort + coalesced flush ---------
// pair = (src << 8) | (dst & 255): 4B packed.
__global__ void part_kernel(const void* __restrict__ ei, int n_edges,
                            int* __restrict__ bcur, unsigned int* __restrict__ pairs,
                            const int* __restrict__ flags, int K) {
    __shared__ int lh[512];                  // counts, then placement cursor
    __shared__ int gdelta[512];              // gstart[b] - lstart[b]
    __shared__ int ts[256];
    __shared__ unsigned int spairs[PART_CH]; // 16 KiB
    __shared__ unsigned short sbkt[PART_CH]; // 8 KiB
    int begin = blockIdx.x * PART_CH;
    int is64 = flags[0];
    int t = threadIdx.x;
    lh[t] = 0; lh[t + 256] = 0;

    int dloc[EPT];
#pragma unroll
    for (int i = 0; i < EPT; ++i) {
        int e = begin + i * 256 + t;
        dloc[i] = (e < n_edges) ? load_dst(ei, n_edges, e, is64) : -1;
    }
    __syncthreads();
#pragma unroll
    for (int i = 0; i < EPT; ++i)
        if (dloc[i] >= 0) atomicAdd(&lh[dloc[i] >> BKT_SHIFT], 1);
    __syncthreads();

    // block scan over 512 bucket counts (thread t owns entries 2t, 2t+1)
    int c0 = lh[2 * t], c1 = lh[2 * t + 1];
    int s = c0 + c1;
    ts[t] = s;
    __syncthreads();
    for (int off = 1; off < 256; off <<= 1) {
        int v = (t >= off) ? ts[t - off] : 0;
        __syncthreads();
        ts[t] += v;
        __syncthreads();
    }
    int ex = ts[t] - s;
    // reserve global runs; cursor = local exclusive start
    if (c0 > 0) gdelta[2 * t]     = atomicAdd(&bcur[2 * t], c0) - ex;
    if (c1 > 0) gdelta[2 * t + 1] = atomicAdd(&bcur[2 * t + 1], c1) - (ex + c0);
    __syncthreads();   // everyone done reading lh counts before overwrite
    lh[2 * t] = ex; lh[2 * t + 1] = ex + c0;
    __syncthreads();

    // place into LDS, sorted by bucket
#pragma unroll
    for (int i = 0; i < EPT; ++i) {
        int e = begin + i * 256 + t;
        if (dloc[i] >= 0) {
            int srcv = load_src(ei, n_edges, e, is64);
            int b = dloc[i] >> BKT_SHIFT;
            int lpos = atomicAdd(&lh[b], 1);
            spairs[lpos] = ((unsigned)srcv << 8) | ((unsigned)dloc[i] & (BKT_W - 1));
            sbkt[lpos] = (unsigned short)b;
        }
    }
    __syncthreads();

    // coalesced flush: ascending j walks bucket runs contiguously
    int total = n_edges - begin; if (total > PART_CH) total = PART_CH;
    for (int j = t; j < total; j += 256)
        pairs[gdelta[sbkt[j]] + j] = spairs[j];
}

// ---------------- per-bucket CSR build (256-node buckets, 512 thr) ----------
__global__ void csr_kernel(const unsigned int* __restrict__ pairs,
                           const int* __restrict__ bucket_off,
                           int* __restrict__ row_off, int* __restrict__ csr_src,
                           int n_nodes) {
    __shared__ int deg[BKT_W];
    __shared__ int cur[BKT_W];
    __shared__ int ts[BKT_W];
    int blk = blockIdx.x;
    int nbase = blk << BKT_SHIFT;
    int NL = n_nodes - nbase; if (NL > BKT_W) NL = BKT_W;
    int beg = bucket_off[blk], end = bucket_off[blk + 1];
    int t = threadIdx.x;
    if (t < BKT_W) deg[t] = 0;
    __syncthreads();
    for (int k = beg + t; k < end; k += blockDim.x)
        atomicAdd(&deg[pairs[k] & (BKT_W - 1)], 1);
    __syncthreads();
    if (t < BKT_W) ts[t] = deg[t];
    __syncthreads();
    for (int off = 1; off < BKT_W; off <<= 1) {
        int v = 0;
        if (t < BKT_W && t >= off) v = ts[t - off];
        __syncthreads();
        if (t < BKT_W) ts[t] += v;
        __syncthreads();
    }
    if (t < BKT_W) {
        int ex = beg + ts[t] - deg[t];
        cur[t] = ex;
        if (t < NL) row_off[nbase + t] = ex;
    }
    __syncthreads();
    for (int k = beg + t; k < end; k += blockDim.x) {
        unsigned int p = pairs[k];
        int pos = atomicAdd(&cur[p & (BKT_W - 1)], 1);
        csr_src[pos] = (int)(p >> 8);
    }
}

// ---------------- gemm1 (MFMA, bf16 x): m1 = x @ W1 -------------------------
__global__ void gemm1_mfma_bf16x(const unsigned short* __restrict__ x,
                                 const void* __restrict__ W1p,
                                 float* __restrict__ m1, int n_nodes,
                                 const int* __restrict__ flags) {
    if (flags[1]) return;              // fp32 x handled elsewhere
    const int wf32 = flags[2];
    __shared__ unsigned short Bl[8 * 64 * 8];  // [kk][lane][j], 8 KiB
    int t = threadIdx.x;
    for (int i = t; i < 4096; i += 256) {      // i = k*16 + n
        unsigned short w = wf32 ? f2bf(((const float*)W1p)[i])
                                : ((const unsigned short*)W1p)[i];
        int k = i >> 4, n = i & 15;
        int kk = k >> 5, quad = (k >> 3) & 3, j = k & 7;
        Bl[((kk * 4 + quad) * 16 + n) * 8 + j] = w;
    }
    __syncthreads();

    int lane = t & 63;
    int wave = t >> 6;
    v8s bfrag[8];
#pragma unroll
    for (int kk = 0; kk < 8; ++kk)
        bfrag[kk] = *(const v8s*)&Bl[(kk * 64 + lane) * 8];

    int col  = lane & 15;
    int quad = lane >> 4;
    int n_tiles = (n_nodes + 15) >> 4;
    for (int tile = blockIdx.x * 4 + wave; tile < n_tiles; tile += gridDim.x * 4) {
        int row = tile * 16 + col;
        int r = row < n_nodes ? row : n_nodes - 1;
        const unsigned short* xp = x + (size_t)r * IN_DIM + quad * 8;
        v4f acc = {0.f, 0.f, 0.f, 0.f};
#pragma unroll
        for (int kk = 0; kk < 8; ++kk) {
            v8s a = *(const v8s*)(xp + kk * 32);
            acc = __builtin_amdgcn_mfma_f32_16x16x32_bf16(a, bfrag[kk], acc, 0, 0, 0);
        }
#pragma unroll
        for (int rg = 0; rg < 4; ++rg) {
            int node = tile * 16 + quad * 4 + rg;
            if (node < n_nodes) m1[(size_t)node * HID + col] = acc[rg];
        }
    }
}

// ---------------- gemm1 (MFMA, fp32 x): split-bf16, fp32-grade precision ----
__global__ void gemm1_mfma_f32x(const float* __restrict__ x,
                                const void* __restrict__ W1p,
                                float* __restrict__ m1, int n_nodes,
                                const int* __restrict__ flags) {
    if (!flags[1]) return;             // bf16 x handled elsewhere
    const int wf32 = flags[2];
    __shared__ unsigned short Bhi[8 * 64 * 8];
    __shared__ unsigned short Blo[8 * 64 * 8];
    int t = threadIdx.x;
    for (int i = t; i < 4096; i += 256) {
        float w = wf32 ? ((const float*)W1p)[i]
                       : bf2f(((const unsigned short*)W1p)[i]);
        unsigned short hi = f2bf(w);
        unsigned short lo = f2bf(w - bf2f(hi));
        int k = i >> 4, n = i & 15;
        int kk = k >> 5, quad = (k >> 3) & 3, j = k & 7;
        int idx = ((kk * 4 + quad) * 16 + n) * 8 + j;
        Bhi[idx] = hi; Blo[idx] = lo;
    }
    __syncthreads();

    int lane = t & 63;
    int wave = t >> 6;
    v8s bhi[8], blo[8];
#pragma unroll
    for (int kk = 0; kk < 8; ++kk) {
        bhi[kk] = *(const v8s*)&Bhi[(kk * 64 + lane) * 8];
        blo[kk] = *(const v8s*)&Blo[(kk * 64 + lane) * 8];
    }

    int col  = lane & 15;
    int quad = lane >> 4;
    int n_tiles = (n_nodes + 15) >> 4;
    for (int tile = blockIdx.x * 4 + wave; tile < n_tiles; tile += gridDim.x * 4) {
        int row = tile * 16 + col;
        int r = row < n_nodes ? row : n_nodes - 1;
        const float* xp = x + (size_t)r * IN_DIM + quad * 8;
        v4f acc = {0.f, 0.f, 0.f, 0.f};
#pragma unroll
        for (int kk = 0; kk < 8; ++kk) {
            float4 u0 = *(const float4*)(xp + kk * 32);
            float4 u1 = *(const float4*)(xp + kk * 32 + 4);
            float uv[8] = {u0.x, u0.y, u0.z, u0.w, u1.x, u1.y, u1.z, u1.w};
            v8s ahi, alo;
#pragma unroll
            for (int j = 0; j < 8; ++j) {
                unsigned short hi = f2bf(uv[j]);
                unsigned short lo = f2bf(uv[j] - bf2f(hi));
                ahi[j] = (short)hi; alo[j] = (short)lo;
            }
            acc = __builtin_amdgcn_mfma_f32_16x16x32_bf16(ahi, bhi[kk], acc, 0, 0, 0);
            acc = __builtin_amdgcn_mfma_f32_16x16x32_bf16(ahi, blo[kk], acc, 0, 0, 0);
            acc = __builtin_amdgcn_mfma_f32_16x16x32_bf16(alo, bhi[kk], acc, 0, 0, 0);
        }
#pragma unroll
        for (int rg = 0; rg < 4; ++rg) {
            int node = tile * 16 + quad * 4 + rg;
            if (node < n_nodes) m1[(size_t)node * HID + col] = acc[rg];
        }
    }
}

// ---------------- gather-sum core: 4 lanes/node, 16-deep MLP ----------------
__device__ __forceinline__ float4 gather_sum16(const float* __restrict__ src,
                                               const int* __restrict__ csr_src,
                                               int beg, int end, int q) {
    float ax = 0.f, ay = 0.f, az = 0.f, aw = 0.f;
    int k = beg;
    for (; k + 16 <= end; k += 16) {
        float4 v[16];
#pragma unroll
        for (int u = 0; u < 16; ++u) {
            int s = csr_src[k + u];
            v[u] = *((const float4*)(src + (size_t)s * HID) + q);
        }
#pragma unroll
        for (int u = 0; u < 16; ++u) {
            ax += v[u].x; ay += v[u].y; az += v[u].z; aw += v[u].w;
        }
    }
    for (; k + 4 <= end; k += 4) {
        float4 v[4];
#pragma unroll
        for (int u = 0; u < 4; ++u) {
            int s = csr_src[k + u];
            v[u] = *((const float4*)(src + (size_t)s * HID) + q);
        }
#pragma unroll
        for (int u = 0; u < 4; ++u) {
            ax += v[u].x; ay += v[u].y; az += v[u].z; aw += v[u].w;
        }
    }
    for (; k < end; ++k) {
        int s = csr_src[k];
        float4 v = *((const float4*)(src + (size_t)s * HID) + q);
        ax += v.x; ay += v.y; az += v.z; aw += v.w;
    }
    return make_float4(ax, ay, az, aw);
}

// ---------------- agg1: h = relu(A . m1 + b1) -------------------------------
__global__ void agg1_kernel(const float* __restrict__ m1,
                            const int* __restrict__ row_off,
                            const int* __restrict__ csr_src,
                            const void* __restrict__ b1p,
                            float* __restrict__ h, int n_nodes,
                            const int* __restrict__ flags) {
    int t = blockIdx.x * blockDim.x + threadIdx.x;
    int node = t >> 2;
    if (node >= n_nodes) return;
    int q = t & 3;
    const int wf32 = flags[2];
    float4 a = gather_sum16(m1, csr_src, row_off[node], row_off[node + 1], q);
    float b0, b1v, b2v, b3;
    if (wf32) {
        const float* b = (const float*)b1p + q * 4;
        b0 = b[0]; b1v = b[1]; b2v = b[2]; b3 = b[3];
    } else {
        const unsigned short* b = (const unsigned short*)b1p + q * 4;
        b0 = bf2f(b[0]); b1v = bf2f(b[1]); b2v = bf2f(b[2]); b3 = bf2f(b[3]);
    }
    float4 r;
    r.x = fmaxf(a.x + b0, 0.f);
    r.y = fmaxf(a.y + b1v, 0.f);
    r.z = fmaxf(a.z + b2v, 0.f);
    r.w = fmaxf(a.w + b3, 0.f);
    *((float4*)(h + (size_t)node * HID) + q) = r;
}

// ---------------- agg2: aggh = A . h ----------------------------------------
__global__ void agg2_kernel(const float* __restrict__ h,
                            const int* __restrict__ row_off,
                            const int* __restrict__ csr_src,
                            float* __restrict__ aggh, int n_nodes) {
    int t = blockIdx.x * blockDim.x + threadIdx.x;
    int node = t >> 2;
    if (node >= n_nodes) return;
    int q = t & 3;
    float4 a = gather_sum16(h, csr_src, row_off[node], row_off[node + 1], q);
    *((float4*)(aggh + (size_t)node * HID) + q) = a;
}

// ---------------- out: out = aggh @ W2 + b2 (assoc: A(hW2) = (Ah)W2) --------
__global__ void out_kernel(const float* __restrict__ aggh,
                           const void* __restrict__ W2p,
                           const void* __restrict__ b2p,
                           void* __restrict__ out, int n_nodes,
                           const int* __restrict__ flags) {
    __shared__ float Ws[HID * OUTD];
    __shared__ float bs[OUTD];
    const int xf32 = flags[1], wf32 = flags[2];
    if (threadIdx.x < HID * OUTD)
        Ws[threadIdx.x] = wf32 ? ((const float*)W2p)[threadIdx.x]
                               : bf2f(((const unsigned short*)W2p)[threadIdx.x]);
    if (threadIdx.x < OUTD)
        bs[threadIdx.x] = wf32 ? ((const float*)b2p)[threadIdx.x]
                               : bf2f(((const unsigned short*)b2p)[threadIdx.x]);
    __syncthreads();

    int i = blockIdx.x * blockDim.x + threadIdx.x;
    if (i >= n_nodes) return;

    float hv[HID];
    const float4* a = (const float4*)(aggh + (size_t)i * HID);
#pragma unroll
    for (int q = 0; q < 4; ++q) {
        float4 v = a[q];
        hv[q * 4 + 0] = v.x; hv[q * 4 + 1] = v.y;
        hv[q * 4 + 2] = v.z; hv[q * 4 + 3] = v.w;
    }
    float o[OUTD];
#pragma unroll
    for (int od = 0; od < OUTD; ++od) {
        float s = bs[od];
#pragma unroll
        for (int c = 0; c < HID; ++c) s = fmaf(hv[c], Ws[c * OUTD + od], s);
        o[od] = s;
    }
    if (xf32) {
        float* po = (float*)out + (size_t)i * OUTD;
#pragma unroll
        for (int od = 0; od < OUTD; ++od) po[od] = o[od];
    } else {
        unsigned int* po = (unsigned int*)((unsigned short*)out + (size_t)i * OUTD);
#pragma unroll
        for (int q = 0; q < 5; ++q)
            po[q] = (unsigned int)f2bf(o[2 * q]) | ((unsigned int)f2bf(o[2 * q + 1]) << 16);
    }
}

// ---------------- Sentinel: ws_size too small -------------------------------
__global__ void sentinel_kernel(float* __restrict__ out) {
    if (blockIdx.x == 0 && threadIdx.x < 16) out[threadIdx.x] = 123456.0f;
}

extern "C" void kernel_launch(void* const* d_in, const int* in_sizes, int n_in,
                              void* d_out, int out_size, void* d_ws, size_t ws_size,
                              hipStream_t stream) {
    const void* x  = d_in[0];
    const void* ei = d_in[1];
    const void* W1 = d_in[2];
    const void* b1 = d_in[3];
    const void* W2 = d_in[4];
    const void* b2 = d_in[5];

    const int n_nodes = in_sizes[0] / IN_DIM;        // 100000
    const int n_edges = in_sizes[1] / 2;             // 3200000
    const int K = (n_nodes + BKT_W - 1) / BKT_W;     // 391 buckets

    // Workspace layout (256B-aligned):
    // [flags | bucket_cnt | bucket_off | bcur | row_off | csr_src |
    //  pairs-region (aliases m1,h,aggh after csr build)]
    char* p = (char*)d_ws;
    auto align = [](size_t v) { return (v + 255) & ~(size_t)255; };
    size_t off = 0;
    int* flags      = (int*)(p + off); off = align(off + 256);
    int* bucket_cnt = (int*)(p + off); off = align(off + (size_t)K * 4);
    int* bucket_off = (int*)(p + off); off = align(off + ((size_t)K + 1) * 4);
    int* bcur       = (int*)(p + off); off = align(off + (size_t)K * 4);
    int* row_off    = (int*)(p + off); off = align(off + ((size_t)n_nodes + 1) * 4);
    int* csr_src    = (int*)(p + off); off = align(off + (size_t)n_edges * 4);
    size_t alias_base = off;
    unsigned int* pairs = (unsigned int*)(p + alias_base);
    float* m1    = (float*)(p + alias_base);          // aliases pairs (stream-ordered)
    float* h     = m1 + (size_t)n_nodes * HID;
    float* aggh  = h  + (size_t)n_nodes * HID;
    size_t alias_sz = (size_t)n_edges * 4;            // packed pairs
    size_t mhm_sz = (size_t)n_nodes * (HID * 3) * 4;
    if (mhm_sz > alias_sz) alias_sz = mhm_sz;
    off = align(alias_base + alias_sz);

    if (ws_size < off) {
        sentinel_kernel<<<1, 64, 0, stream>>>((float*)d_out);
        return;
    }

    const size_t lds_k = (size_t)K * 4;

    // --- CSR build (bucketed, LDS counting-sort, line-efficient writes) ---
    setup_kernel<<<1, 256, 0, stream>>>(x, W1, ei, n_nodes, flags, bucket_cnt, K);
    bhist_kernel<<<1024, 256, lds_k, stream>>>(ei, n_edges, bucket_cnt, flags, K);
    bscan_kernel<<<1, 256, 0, stream>>>(bucket_cnt, K, bucket_off, bcur,
                                        row_off, n_nodes, n_edges);
    part_kernel<<<(n_edges + PART_CH - 1) / PART_CH, 256, 0, stream>>>(
        ei, n_edges, bcur, pairs, flags, K);
    csr_kernel<<<K, 512, 0, stream>>>(pairs, bucket_off, row_off, csr_src, n_nodes);

    // --- layer 1 ---
    gemm1_mfma_bf16x<<<512, 256, 0, stream>>>(
        (const unsigned short*)x, W1, m1, n_nodes, flags);
    gemm1_mfma_f32x<<<512, 256, 0, stream>>>(
        (const float*)x, W1, m1, n_nodes, flags);
    {
        long long threads = (long long)n_nodes * 4;
        agg1_kernel<<<(int)((threads + 255) / 256), 256, 0, stream>>>(
            m1, row_off, csr_src, b1, h, n_nodes, flags);
    }

    // --- layer 2 (assoc: out = (A.h)@W2 + b2) ---
    {
        long long threads = (long long)n_nodes * 4;
        agg2_kernel<<<(int)((threads + 255) / 256), 256, 0, stream>>>(
            h, row_off, csr_src, aggh, n_nodes);
    }
    out_kernel<<<(n_nodes + 255) / 256, 256, 0, stream>>>(
        aggh, W2, b2, d_out, n_nodes, flags);
}